// Round 13
// baseline (255.704 us; speedup 1.0000x reference)
//
#include <hip/hip_runtime.h>
#include <hip/hip_bf16.h>

typedef __attribute__((ext_vector_type(4))) float f32x4;
typedef __attribute__((ext_vector_type(8))) int i32x8;

#define T_TOK 1370
#define DDIM  768
#define SCV   1369   // valid tokens per slab
#define SCP   1408   // s slab padded rows (11*128)
#define MQP   1536   // q padded rows (6*256)
#define NB    8
#define NSLAB 32
#define NST   22     // s supertiles of 256 (4*1408/256)
#define NMT   6      // m tiles of 256

#define MEMFENCE asm volatile("" ::: "memory")

#define GLOAD_LDS16(g, l)                                                     \
  __builtin_amdgcn_global_load_lds(                                           \
      (const __attribute__((address_space(1))) unsigned int*)(g),             \
      (__attribute__((address_space(3))) unsigned int*)(l), 16, 0, 0)

// One block per output row: mean over 3 layers -> l2norm -> fp8 e4m3 store.
// dst layout: [slabs][pad][768] fp8, rows >= 1369 zeroed. pad via gridDim.x.
extern "C" __global__ __launch_bounds__(192) void prep_kernel(
    const float* __restrict__ src, unsigned char* __restrict__ dst,
    size_t lstride)
{
  const int row  = blockIdx.x;
  const int slab = blockIdx.y;
  const int t    = threadIdx.x;  // 0..191, each owns one float4 (768 = 192*4)
  unsigned char* drow = dst + ((size_t)slab * gridDim.x + row) * DDIM;
  if (row >= SCV) {
    reinterpret_cast<unsigned int*>(drow)[t] = 0u;
    return;
  }
  const float* base = src + ((size_t)slab * T_TOK + row + 1) * DDIM;
  float4 a = reinterpret_cast<const float4*>(base)[t];
  float4 b = reinterpret_cast<const float4*>(base + lstride)[t];
  float4 c = reinterpret_cast<const float4*>(base + 2 * lstride)[t];
  const float k3 = 1.0f / 3.0f;
  float4 m;
  m.x = (a.x + b.x + c.x) * k3;
  m.y = (a.y + b.y + c.y) * k3;
  m.z = (a.z + b.z + c.z) * k3;
  m.w = (a.w + b.w + c.w) * k3;
  float ss = m.x * m.x + m.y * m.y + m.z * m.z + m.w * m.w;
  #pragma unroll
  for (int d = 1; d < 64; d <<= 1) ss += __shfl_xor(ss, d);
  __shared__ float wsum[3];
  if ((t & 63) == 0) wsum[t >> 6] = ss;
  __syncthreads();
  float tot = wsum[0] + wsum[1] + wsum[2];
  float rn = 1.0f / fmaxf(sqrtf(tot), 1e-12f);
  int pk = __builtin_amdgcn_cvt_pk_fp8_f32(m.x * rn, m.y * rn, 0, false);
  pk = __builtin_amdgcn_cvt_pk_fp8_f32(m.z * rn, m.w * rn, pk, true);
  reinterpret_cast<unsigned int*>(drow)[t] = (unsigned int)pk;
}

// 256x256 tile, BK=128, MX-fp8 16x16x128 (scale=1.0), 8 waves (2M x 4N,
// per-wave 128x64). A read DIRECTLY global->VGPR (L1/L2-served, no LDS);
// only B double-buffered in LDS (64 KB) => 2 blocks/CU. 6 K-steps.
// Grid 1056 = 8 XCD-chunks x 132. part: [8][22][1536] float.
extern "C" __global__ __launch_bounds__(512, 2) void simmax_kernel(
    const unsigned char* __restrict__ xq,
    const unsigned char* __restrict__ xs,
    float* __restrict__ part)
{
  // XCD-chunked bijective remap: nwg = 1056 = 8*132; XCD k owns batch n=k,
  // mt varies fastest so 6 consecutive blocks share one B supertile.
  const int flat = blockIdx.x;
  const int swz  = (flat & 7) * (NMT * NST) + (flat >> 3);
  const int n    = swz / (NMT * NST);
  const int idx  = swz - n * (NMT * NST);
  const int mt   = idx % NMT;
  const int st   = idx / NMT;

  const int tid  = threadIdx.x;  // 0..511
  const int lane = tid & 63;
  const int w    = tid >> 6;     // 0..7
  const int wr   = w >> 2;       // 0..1 : 128-row half of 256
  const int wcn  = w & 3;        // 0..3 : 64-col quarter of 256
  const int l15  = lane & 15, l4 = lane >> 4;

  __shared__ unsigned char bbuf[2][32768];  // B dbuf: 256 rows x 128 B
  __shared__ float sfold[1024];

  const unsigned char* gA = xq + ((size_t)n * MQP + (size_t)mt * 256) * DDIM;
  const unsigned char* gB = xs + ((size_t)n * 4 * SCP + (size_t)st * 256) * DDIM;

  // B staging: 32 chunks of 1 KB (8 rows x 128 B); wave owns chunks w*4..+3.
  // lane -> row c*8+(lane>>3), 16-B slot lane&7. Source pre-swizzled
  // slot^(row&7); LDS dest linear; reads XOR the same involution.
  int goff[4], ldso[4];
  #pragma unroll
  for (int i = 0; i < 4; ++i) {
    int c = w * 4 + i;
    int r = c * 8 + (lane >> 3);
    goff[i] = r * DDIM + (((lane & 7) ^ (r & 7)) << 4);
    ldso[i] = c * 1024;
  }

  // A fragment global byte offsets: row = wr*128 + mf*16 + l15, k0 = l4*32.
  int aoffg[8];
  #pragma unroll
  for (int mf = 0; mf < 8; ++mf)
    aoffg[mf] = (wr * 128 + mf * 16 + l15) * DDIM + l4 * 32;

  // B fragment LDS byte offsets (swizzled): two b128 at off and off^16.
  int boff[4];
  #pragma unroll
  for (int nf = 0; nf < 4; ++nf) {
    int row = wcn * 64 + nf * 16 + l15;
    boff[nf] = row * 128 + ((((l4 << 1) ^ (row & 7))) << 4);
  }

  f32x4 acc[8][4];
  {
    f32x4 zz = {0.f, 0.f, 0.f, 0.f};
    #pragma unroll
    for (int a = 0; a < 8; ++a)
      #pragma unroll
      for (int b = 0; b < 4; ++b) acc[a][b] = zz;
  }

  #define ISSUE_B(KT, RB)                                                    \
    do {                                                                     \
      const unsigned char* gb_ = gB + (KT) * 128;                            \
      unsigned char* lb_ = bbuf[RB];                                         \
      _Pragma("unroll") for (int i = 0; i < 4; ++i)                          \
        GLOAD_LDS16(gb_ + goff[i], lb_ + ldso[i]);                           \
    } while (0)

  ISSUE_B(0, 0);
  __syncthreads();

  for (int kt = 0; kt < 6; ++kt) {
    if (kt + 1 < 6) ISSUE_B(kt + 1, (kt + 1) & 1);

    const char* Cb = reinterpret_cast<const char*>(bbuf[kt & 1]);
    i32x8 bfr[4];
    #pragma unroll
    for (int nf = 0; nf < 4; ++nf) {
      int4 lo = *reinterpret_cast<const int4*>(Cb + boff[nf]);
      int4 hi = *reinterpret_cast<const int4*>(Cb + (boff[nf] ^ 16));
      bfr[nf] = i32x8{lo.x, lo.y, lo.z, lo.w, hi.x, hi.y, hi.z, hi.w};
    }

    const unsigned char* ga = gA + kt * 128;
    __builtin_amdgcn_s_setprio(1);
    #pragma unroll
    for (int mf = 0; mf < 8; ++mf) {
      int4 lo = *reinterpret_cast<const int4*>(ga + aoffg[mf]);
      int4 hi = *reinterpret_cast<const int4*>(ga + aoffg[mf] + 16);
      i32x8 af = i32x8{lo.x, lo.y, lo.z, lo.w, hi.x, hi.y, hi.z, hi.w};
      #pragma unroll
      for (int nf = 0; nf < 4; ++nf)
        acc[mf][nf] = __builtin_amdgcn_mfma_scale_f32_16x16x128_f8f6f4(
            af, bfr[nf], acc[mf][nf], 0, 0, 0, 127, 0, 127);
    }
    __builtin_amdgcn_s_setprio(0);

    __syncthreads();   // drains B-stage (issued a full step ago) + LDS reads
  }

  // ---- epilogue: masked running max, butterfly over 16 col-lanes ----
  bool colv[4];
  #pragma unroll
  for (int nf = 0; nf < 4; ++nf) {
    int col = st * 256 + wcn * 64 + nf * 16 + l15;   // 0..5631
    int within = col - (col / SCP) * SCP;
    colv[nf] = within < SCV;
  }

  float rm[8][4];
  #pragma unroll
  for (int mf = 0; mf < 8; ++mf)
    #pragma unroll
    for (int j = 0; j < 4; ++j) {
      float v = -1e30f;
      #pragma unroll
      for (int nf = 0; nf < 4; ++nf)
        if (colv[nf]) v = fmaxf(v, acc[mf][nf][j]);
      rm[mf][j] = v;
    }

  #pragma unroll
  for (int msk = 1; msk < 16; msk <<= 1)
    #pragma unroll
    for (int mf = 0; mf < 8; ++mf)
      #pragma unroll
      for (int j = 0; j < 4; ++j)
        rm[mf][j] = fmaxf(rm[mf][j], __shfl_xor(rm[mf][j], msk));

  __syncthreads();
  if (l15 == 0) {
    #pragma unroll
    for (int mf = 0; mf < 8; ++mf)
      #pragma unroll
      for (int j = 0; j < 4; ++j) {
        int r = wr * 128 + mf * 16 + l4 * 4 + j;   // 0..255
        sfold[wcn * 256 + r] = rm[mf][j];
      }
  }
  __syncthreads();
  if (tid < 256) {
    float v = fmaxf(fmaxf(sfold[tid], sfold[256 + tid]),
                    fmaxf(sfold[512 + tid], sfold[768 + tid]));
    part[((size_t)n * NST + st) * MQP + (size_t)mt * 256 + tid] = v;
  }
}

extern "C" __global__ void finalize_kernel(const float* __restrict__ part,
                                           float* __restrict__ out) {
  int i = blockIdx.x * 256 + threadIdx.x;
  if (i >= NB * SCV) return;
  int n = i / SCV, q = i - n * SCV;
  const float* p = part + (size_t)n * NST * MQP + q;
  float m = p[0];
  #pragma unroll 4
  for (int g = 1; g < NST; ++g) m = fmaxf(m, p[(size_t)g * MQP]);
  out[i] = 1.0f - m;
}

extern "C" void kernel_launch(void* const* d_in, const int* in_sizes, int n_in,
                              void* d_out, int out_size, void* d_ws, size_t ws_size,
                              hipStream_t stream) {
  const float* q_feats = (const float*)d_in[0];  // (3, 8, 1370, 768) f32
  const float* s_feats = (const float*)d_in[1];  // (3, 32, 1370, 768) f32
  float* out = (float*)d_out;                    // (8, 1, 37, 37) f32

  char* ws = (char*)d_ws;
  const size_t xq_bytes = (size_t)NB * MQP * DDIM;     // 9,437,184 (fp8)
  const size_t xs_bytes = (size_t)NSLAB * SCP * DDIM;  // 34,603,008 (fp8)
  unsigned char* xq = (unsigned char*)ws;
  unsigned char* xs = (unsigned char*)(ws + xq_bytes);
  float* part       = (float*)(ws + xq_bytes + xs_bytes); // 8*22*1536 floats

  prep_kernel<<<dim3(MQP, NB), 192, 0, stream>>>(
      q_feats, xq, (size_t)NB * T_TOK * DDIM);
  prep_kernel<<<dim3(SCP, NSLAB), 192, 0, stream>>>(
      s_feats, xs, (size_t)NSLAB * T_TOK * DDIM);
  simmax_kernel<<<dim3(NB * NMT * NST), 512, 0, stream>>>(xq, xs, part);
  finalize_kernel<<<dim3((NB * SCV + 255) / 256), 256, 0, stream>>>(part, out);
}

// Round 14
// 192.992 us; speedup vs baseline: 1.3249x; 1.3249x over previous
//
#include <hip/hip_runtime.h>
#include <hip/hip_bf16.h>

typedef __attribute__((ext_vector_type(4))) float f32x4;
typedef __attribute__((ext_vector_type(8))) int i32x8;

#define T_TOK 1370
#define DDIM  768
#define SCV   1369   // valid tokens per slab
#define SCP   1408   // s slab padded rows (11*128)
#define MQP   1536   // q padded rows (6*256)
#define NB    8
#define NSLAB 32
#define NST   22     // s supertiles of 256 (4*1408/256)
#define NMT   6      // m tiles of 256

#define MEMFENCE asm volatile("" ::: "memory")
#define BARRIER  do { __builtin_amdgcn_s_barrier(); MEMFENCE; } while (0)
#define LGKM0    asm volatile("s_waitcnt lgkmcnt(0)" ::: "memory")

#define GLOAD_LDS16(g, l)                                                     \
  __builtin_amdgcn_global_load_lds(                                           \
      (const __attribute__((address_space(1))) unsigned int*)(g),             \
      (__attribute__((address_space(3))) unsigned int*)(l), 16, 0, 0)

// One block per output row: mean over 3 layers -> l2norm -> fp8 e4m3 store.
// dst layout: [slabs][pad][768] fp8, rows >= 1369 zeroed. pad via gridDim.x.
extern "C" __global__ __launch_bounds__(192) void prep_kernel(
    const float* __restrict__ src, unsigned char* __restrict__ dst,
    size_t lstride)
{
  const int row  = blockIdx.x;
  const int slab = blockIdx.y;
  const int t    = threadIdx.x;  // 0..191, each owns one float4 (768 = 192*4)
  unsigned char* drow = dst + ((size_t)slab * gridDim.x + row) * DDIM;
  if (row >= SCV) {
    reinterpret_cast<unsigned int*>(drow)[t] = 0u;
    return;
  }
  const float* base = src + ((size_t)slab * T_TOK + row + 1) * DDIM;
  float4 a = reinterpret_cast<const float4*>(base)[t];
  float4 b = reinterpret_cast<const float4*>(base + lstride)[t];
  float4 c = reinterpret_cast<const float4*>(base + 2 * lstride)[t];
  const float k3 = 1.0f / 3.0f;
  float4 m;
  m.x = (a.x + b.x + c.x) * k3;
  m.y = (a.y + b.y + c.y) * k3;
  m.z = (a.z + b.z + c.z) * k3;
  m.w = (a.w + b.w + c.w) * k3;
  float ss = m.x * m.x + m.y * m.y + m.z * m.z + m.w * m.w;
  #pragma unroll
  for (int d = 1; d < 64; d <<= 1) ss += __shfl_xor(ss, d);
  __shared__ float wsum[3];
  if ((t & 63) == 0) wsum[t >> 6] = ss;
  __syncthreads();
  float tot = wsum[0] + wsum[1] + wsum[2];
  float rn = 1.0f / fmaxf(sqrtf(tot), 1e-12f);
  int pk = __builtin_amdgcn_cvt_pk_fp8_f32(m.x * rn, m.y * rn, 0, false);
  pk = __builtin_amdgcn_cvt_pk_fp8_f32(m.z * rn, m.w * rn, pk, true);
  reinterpret_cast<unsigned int*>(drow)[t] = (unsigned int)pk;
}

// 256x256 tile, BK=128, MX-fp8 16x16x128 (scale=1.0), 8 waves (2M x 4N,
// per-wave 128x64). A dbuf-2 (64 KB) + B ring-3 (96 KB) = 160 KiB LDS.
// Counted vmcnt(4): B(kt+2) stays in flight across the end-of-step wait.
// 4 MFMA phases/step (mf-pairs) with lgkmcnt+setprio role-split.
// Grid 1056 = 8 XCD-chunks x 132. part: [8][22][1536] float.
extern "C" __global__ __launch_bounds__(512, 2) void simmax_kernel(
    const unsigned char* __restrict__ xq,
    const unsigned char* __restrict__ xs,
    float* __restrict__ part)
{
  // XCD-chunked bijective remap: nwg = 1056 = 8*132; XCD k owns batch n=k,
  // mt varies fastest so 6 consecutive blocks share one B supertile.
  const int flat = blockIdx.x;
  const int swz  = (flat & 7) * (NMT * NST) + (flat >> 3);
  const int n    = swz / (NMT * NST);
  const int idx  = swz - n * (NMT * NST);
  const int mt   = idx % NMT;
  const int st   = idx / NMT;

  const int tid  = threadIdx.x;  // 0..511
  const int lane = tid & 63;
  const int w    = tid >> 6;     // 0..7
  const int wr   = w >> 2;       // 0..1 : 128-row half of 256
  const int wcn  = w & 3;        // 0..3 : 64-col quarter of 256
  const int l15  = lane & 15, l4 = lane >> 4;

  __shared__ unsigned char Abuf[2][32768];  //  64 KB
  __shared__ unsigned char Bbuf[3][32768];  //  96 KB  (total 160 KiB exact)

  const unsigned char* gA = xq + ((size_t)n * MQP + (size_t)mt * 256) * DDIM;
  const unsigned char* gB = xs + ((size_t)n * 4 * SCP + (size_t)st * 256) * DDIM;

  // staging: 32 chunks of 1 KB (8 rows x 128 B) per matrix; wave owns chunks
  // w*4..+3. lane -> row c*8+(lane>>3), 16-B slot lane&7. Source pre-swizzled
  // slot^(row&7); LDS dest linear; reads XOR the same involution.
  int goff[4], ldso[4];
  #pragma unroll
  for (int i = 0; i < 4; ++i) {
    int c = w * 4 + i;
    int r = c * 8 + (lane >> 3);
    goff[i] = r * DDIM + (((lane & 7) ^ (r & 7)) << 4);
    ldso[i] = c * 1024;
  }

  // fragment read byte offsets: two b128 at off and off^16 per 32-B frag.
  int aoff[8], boff[4];
  #pragma unroll
  for (int mf = 0; mf < 8; ++mf) {
    int row = wr * 128 + mf * 16 + l15;
    aoff[mf] = row * 128 + ((((l4 << 1) ^ (row & 7))) << 4);
  }
  #pragma unroll
  for (int nf = 0; nf < 4; ++nf) {
    int row = wcn * 64 + nf * 16 + l15;
    boff[nf] = row * 128 + ((((l4 << 1) ^ (row & 7))) << 4);
  }

  f32x4 acc[8][4];
  {
    f32x4 zz = {0.f, 0.f, 0.f, 0.f};
    #pragma unroll
    for (int a = 0; a < 8; ++a)
      #pragma unroll
      for (int b = 0; b < 4; ++b) acc[a][b] = zz;
  }

  #define ISSUE_A(KT)                                                        \
    do {                                                                     \
      const unsigned char* ga_ = gA + (KT) * 128;                            \
      unsigned char* la_ = Abuf[(KT) & 1];                                   \
      _Pragma("unroll") for (int i = 0; i < 4; ++i)                          \
        GLOAD_LDS16(ga_ + goff[i], la_ + ldso[i]);                           \
    } while (0)
  #define ISSUE_B(KT)                                                        \
    do {                                                                     \
      const unsigned char* gb_ = gB + (KT) * 128;                            \
      unsigned char* lb_ = Bbuf[(KT) % 3];                                   \
      _Pragma("unroll") for (int i = 0; i < 4; ++i)                          \
        GLOAD_LDS16(gb_ + goff[i], lb_ + ldso[i]);                           \
    } while (0)

  #define READ_FRAG(PTR, OFF, DST)                                           \
    do {                                                                     \
      int4 lo_ = *reinterpret_cast<const int4*>((PTR) + (OFF));              \
      int4 hi_ = *reinterpret_cast<const int4*>((PTR) + ((OFF) ^ 16));       \
      DST = i32x8{lo_.x, lo_.y, lo_.z, lo_.w, hi_.x, hi_.y, hi_.z, hi_.w};   \
    } while (0)

  // prologue: A(0), B(0), B(1); wait for A(0)+B(0) (8 oldest), keep B(1).
  ISSUE_A(0);
  ISSUE_B(0);
  ISSUE_B(1);
  asm volatile("s_waitcnt vmcnt(4)" ::: "memory");
  BARRIER;

  for (int kt = 0; kt < 6; ++kt) {
    // top: issue next stages (A older than B => vmcnt(4) waits A, floats B)
    if (kt < 5) ISSUE_A(kt + 1);
    if (kt < 4) ISSUE_B(kt + 2);

    const char* Ab = reinterpret_cast<const char*>(Abuf[kt & 1]);
    const char* Bb = reinterpret_cast<const char*>(Bbuf[kt % 3]);

    // ---- ph0: all B frags + A mf0,1 ----
    i32x8 bfr[4], af0, af1;
    #pragma unroll
    for (int nf = 0; nf < 4; ++nf) READ_FRAG(Bb, boff[nf], bfr[nf]);
    READ_FRAG(Ab, aoff[0], af0);
    READ_FRAG(Ab, aoff[1], af1);
    BARRIER; LGKM0;
    __builtin_amdgcn_s_setprio(1);
    #pragma unroll
    for (int nf = 0; nf < 4; ++nf) {
      acc[0][nf] = __builtin_amdgcn_mfma_scale_f32_16x16x128_f8f6f4(
          af0, bfr[nf], acc[0][nf], 0, 0, 0, 127, 0, 127);
      acc[1][nf] = __builtin_amdgcn_mfma_scale_f32_16x16x128_f8f6f4(
          af1, bfr[nf], acc[1][nf], 0, 0, 0, 127, 0, 127);
    }
    __builtin_amdgcn_s_setprio(0);
    BARRIER;

    // ---- ph1..ph3: A mf-pairs ----
    #pragma unroll
    for (int p = 1; p < 4; ++p) {
      i32x8 afa, afb;
      READ_FRAG(Ab, aoff[2 * p], afa);
      READ_FRAG(Ab, aoff[2 * p + 1], afb);
      if (p == 3) {  // end-of-step wait: A(kt+1)+B(kt+1) landed, B(kt+2) flies
        if (kt < 4)       asm volatile("s_waitcnt vmcnt(4)" ::: "memory");
        else if (kt == 4) asm volatile("s_waitcnt vmcnt(0)" ::: "memory");
      }
      BARRIER; LGKM0;
      __builtin_amdgcn_s_setprio(1);
      #pragma unroll
      for (int nf = 0; nf < 4; ++nf) {
        acc[2 * p][nf] = __builtin_amdgcn_mfma_scale_f32_16x16x128_f8f6f4(
            afa, bfr[nf], acc[2 * p][nf], 0, 0, 0, 127, 0, 127);
        acc[2 * p + 1][nf] = __builtin_amdgcn_mfma_scale_f32_16x16x128_f8f6f4(
            afb, bfr[nf], acc[2 * p + 1][nf], 0, 0, 0, 127, 0, 127);
      }
      __builtin_amdgcn_s_setprio(0);
      BARRIER;
    }
  }

  // ---- epilogue: masked running max, butterfly over 16 col-lanes ----
  bool colv[4];
  #pragma unroll
  for (int nf = 0; nf < 4; ++nf) {
    int col = st * 256 + wcn * 64 + nf * 16 + l15;   // 0..5631
    int within = col - (col / SCP) * SCP;
    colv[nf] = within < SCV;
  }

  float rm[8][4];
  #pragma unroll
  for (int mf = 0; mf < 8; ++mf)
    #pragma unroll
    for (int j = 0; j < 4; ++j) {
      float v = -1e30f;
      #pragma unroll
      for (int nf = 0; nf < 4; ++nf)
        if (colv[nf]) v = fmaxf(v, acc[mf][nf][j]);
      rm[mf][j] = v;
    }

  #pragma unroll
  for (int msk = 1; msk < 16; msk <<= 1)
    #pragma unroll
    for (int mf = 0; mf < 8; ++mf)
      #pragma unroll
      for (int j = 0; j < 4; ++j)
        rm[mf][j] = fmaxf(rm[mf][j], __shfl_xor(rm[mf][j], msk));

  __syncthreads();
  float* sfold = reinterpret_cast<float*>(&Abuf[0][0]);  // 1024 floats
  if (l15 == 0) {
    #pragma unroll
    for (int mf = 0; mf < 8; ++mf)
      #pragma unroll
      for (int j = 0; j < 4; ++j) {
        int r = wr * 128 + mf * 16 + l4 * 4 + j;   // 0..255
        sfold[wcn * 256 + r] = rm[mf][j];
      }
  }
  __syncthreads();
  if (tid < 256) {
    float v = fmaxf(fmaxf(sfold[tid], sfold[256 + tid]),
                    fmaxf(sfold[512 + tid], sfold[768 + tid]));
    part[((size_t)n * NST + st) * MQP + (size_t)mt * 256 + tid] = v;
  }
}

extern "C" __global__ void finalize_kernel(const float* __restrict__ part,
                                           float* __restrict__ out) {
  int i = blockIdx.x * 256 + threadIdx.x;
  if (i >= NB * SCV) return;
  int n = i / SCV, q = i - n * SCV;
  const float* p = part + (size_t)n * NST * MQP + q;
  float m = p[0];
  #pragma unroll 4
  for (int g = 1; g < NST; ++g) m = fmaxf(m, p[(size_t)g * MQP]);
  out[i] = 1.0f - m;
}

extern "C" void kernel_launch(void* const* d_in, const int* in_sizes, int n_in,
                              void* d_out, int out_size, void* d_ws, size_t ws_size,
                              hipStream_t stream) {
  const float* q_feats = (const float*)d_in[0];  // (3, 8, 1370, 768) f32
  const float* s_feats = (const float*)d_in[1];  // (3, 32, 1370, 768) f32
  float* out = (float*)d_out;                    // (8, 1, 37, 37) f32

  char* ws = (char*)d_ws;
  const size_t xq_bytes = (size_t)NB * MQP * DDIM;     // 9,437,184 (fp8)
  const size_t xs_bytes = (size_t)NSLAB * SCP * DDIM;  // 34,603,008 (fp8)
  unsigned char* xq = (unsigned char*)ws;
  unsigned char* xs = (unsigned char*)(ws + xq_bytes);
  float* part       = (float*)(ws + xq_bytes + xs_bytes); // 8*22*1536 floats

  prep_kernel<<<dim3(MQP, NB), 192, 0, stream>>>(
      q_feats, xq, (size_t)NB * T_TOK * DDIM);
  prep_kernel<<<dim3(SCP, NSLAB), 192, 0, stream>>>(
      s_feats, xs, (size_t)NSLAB * T_TOK * DDIM);
  simmax_kernel<<<dim3(NB * NMT * NST), 512, 0, stream>>>(xq, xs, part);
  finalize_kernel<<<dim3((NB * SCV + 255) / 256), 256, 0, stream>>>(part, out);
}